// Round 1
// baseline (416.854 us; speedup 1.0000x reference)
//
#include <hip/hip_runtime.h>

// GraphSageConvOD: 2-iteration OD flow + SIR propagation + 12x64 dense + ReLU.
// B=8, T=2, N=2048. OD_all is 256 MB fp32 and dominates; memory-bound.
//
// Structure:
//   A  rowsum_kernel : row sums of OD_all for both t (raw OD, state-independent)
//   B0 prep0_kernel  : scale0, w0 = scale0*[1, SIR_n0], pm0/stay0 (analytic OD_out)
//   C0 colacc<4,4>   : acc0[b,j,f] = sum_i OD0[b,i,j]*w0[b,i,f]   (atomicAdd)
//   B1 prep1_kernel  : pop1/SIR1 from pm0+acc0; scale1, w1, pm1/stay1
//   C1 colacc<7,8>   : acc1[b,j,f] = sum_i OD1[b,i,j]*w1[b,i,f]
//   D  final_kernel  : SIR2 (12f) @ kernel(12x64) + bias, relu; concat pop2

#define DELTA 1e-7f
constexpr int B = 8, N = 2048, T = 2;
constexpr int NB = B * N; // 16384

// ws layout (float offsets)
constexpr int RS_OFF   = 0;                 // row sums [t][b][i]  : 2*NB
constexpr int W0_OFF   = RS_OFF  + 2 * NB;  // w0  [b][i][4]
constexpr int ST0_OFF  = W0_OFF  + NB * 4;  // {pm0, stay0[3]}
constexpr int W1_OFF   = ST0_OFF + NB * 4;  // w1  [b][i][8] (7 used)
constexpr int ST1_OFF  = W1_OFF  + NB * 8;  // {pm1, stay1[6], pad}
constexpr int ACC0_OFF = ST1_OFF + NB * 8;  // acc0 [b][j][4]  (zeroed)
constexpr int ACC1_OFF = ACC0_OFF + NB * 4; // acc1 [b][j][7]  (zeroed)
constexpr int WS_END   = ACC1_OFF + NB * 7;

// ---- A: one wave per row; 2048 floats = 8 float4 per lane ----
__global__ void __launch_bounds__(256) rowsum_kernel(const float* __restrict__ OD,
                                                     float* __restrict__ rs) {
  const int quad = threadIdx.x >> 6, lane = threadIdx.x & 63;
  const int r = blockIdx.x * 4 + quad;  // flat row over [b][t][i], 0..32767
  const float4* p = (const float4*)(OD + (size_t)r * N);
  float s = 0.f;
#pragma unroll
  for (int k = 0; k < 8; ++k) {
    float4 v = p[lane + 64 * k];
    s += (v.x + v.y) + (v.z + v.w);
  }
#pragma unroll
  for (int off = 32; off; off >>= 1) s += __shfl_down(s, off, 64);
  if (lane == 0) {
    const int b = r >> 12, t = (r >> 11) & 1, i = r & (N - 1);
    rs[t * NB + b * N + i] = s;
  }
}

// ---- B0: per-(b,i) iteration-0 prep ----
__global__ void __launch_bounds__(256) prep0_kernel(const float* __restrict__ feat,
                                                    const float* __restrict__ rs,
                                                    float* __restrict__ w0,
                                                    float* __restrict__ st0) {
  const int g = blockIdx.x * 256 + threadIdx.x;  // b*N+i
  const float4 f = ((const float4*)feat)[g];
  const float pop = f.x;
  const float rs0 = rs[g];
  const float ratio = pop / (DELTA + rs0);
  const float scale = ratio < 1.f ? ratio : 1.f;
  const float inv = 1.f / (DELTA + pop);
  const float sn0 = f.y * inv, sn1 = f.z * inv, sn2 = f.w * inv;
  const float odout = scale * rs0;
  ((float4*)w0)[g]  = make_float4(scale, scale * sn0, scale * sn1, scale * sn2);
  ((float4*)st0)[g] = make_float4(pop - odout, f.y - odout * sn0,
                                  f.z - odout * sn1, f.w - odout * sn2);
}

// ---- C: acc[b,j,f] += sum_i OD[b,t,i,j] * w[b,i,f]
// 256x256 tile per block; thread = (quad rows) x (lane -> 4 cols, float4)
template <int NF, int WSTRIDE>
__global__ void __launch_bounds__(256) colacc_kernel(const float* __restrict__ OD_all,
                                                     const int t,
                                                     const float* __restrict__ w,
                                                     float* __restrict__ acc) {
  const int tid = threadIdx.x;
  const int quad = tid >> 6, lane = tid & 63;
  const int jbase = blockIdx.x * 256;
  const int ibase = blockIdx.y * 256;
  const int b = blockIdx.z;

  __shared__ float wlds[256 * WSTRIDE];
  {
    const float4* src = (const float4*)(w + (size_t)(b * N + ibase) * WSTRIDE);
    float4* dst = (float4*)wlds;
#pragma unroll
    for (int x = tid; x < 256 * WSTRIDE / 4; x += 256) dst[x] = src[x];
  }
  __syncthreads();

  float accr[4][NF];
#pragma unroll
  for (int c = 0; c < 4; ++c)
#pragma unroll
    for (int f = 0; f < NF; ++f) accr[c][f] = 0.f;

  const float* odbase =
      OD_all + ((size_t)(b * T + t) * N + ibase) * N + jbase + lane * 4;
  for (int k = 0; k < 64; ++k) {
    const int r = quad + 4 * k;
    const float4 od = *(const float4*)(odbase + (size_t)r * N);
#pragma unroll
    for (int f = 0; f < NF; ++f) {
      const float wv = wlds[r * WSTRIDE + f];  // wave-uniform -> broadcast
      accr[0][f] += od.x * wv;
      accr[1][f] += od.y * wv;
      accr[2][f] += od.z * wv;
      accr[3][f] += od.w * wv;
    }
  }
  __syncthreads();

  __shared__ float red[4][256 * NF];
#pragma unroll
  for (int c = 0; c < 4; ++c)
#pragma unroll
    for (int f = 0; f < NF; ++f)
      red[quad][(lane * 4 + c) * NF + f] = accr[c][f];
  __syncthreads();

  for (int x = tid; x < 256 * NF; x += 256) {
    const float s = red[0][x] + red[1][x] + red[2][x] + red[3][x];
    const int colx = x / NF, f = x - colx * NF;
    atomicAdd(&acc[(size_t)(b * N + jbase + colx) * NF + f], s);
  }
}

// ---- B1: per-(b,j) iteration-1 prep ----
__global__ void __launch_bounds__(256) prep1_kernel(const float* __restrict__ st0,
                                                    const float* __restrict__ acc0,
                                                    const float* __restrict__ rs,
                                                    float* __restrict__ w1,
                                                    float* __restrict__ st1) {
  const int g = blockIdx.x * 256 + threadIdx.x;
  const float4 s0 = ((const float4*)st0)[g];
  const float4 a0 = ((const float4*)acc0)[g];
  const float rs1 = rs[NB + g];
  const float pop = s0.x + a0.x;  // pm0 + OD_in0
  const float S[6] = {s0.y, s0.z, s0.w, a0.y, a0.z, a0.w};  // [stay0, in0]
  const float ratio = pop / (DELTA + rs1);
  const float scale = ratio < 1.f ? ratio : 1.f;
  const float inv = 1.f / (DELTA + pop);
  const float odout = scale * rs1;
  float wv[8], sv[8];
  wv[0] = scale;
  sv[0] = pop - odout;
#pragma unroll
  for (int f = 0; f < 6; ++f) {
    const float sn = S[f] * inv;
    wv[1 + f] = scale * sn;
    sv[1 + f] = S[f] - odout * sn;
  }
  wv[7] = 0.f;
  sv[7] = 0.f;
  float4* w4 = (float4*)(w1 + (size_t)g * 8);
  w4[0] = make_float4(wv[0], wv[1], wv[2], wv[3]);
  w4[1] = make_float4(wv[4], wv[5], wv[6], wv[7]);
  float4* s4 = (float4*)(st1 + (size_t)g * 8);
  s4[0] = make_float4(sv[0], sv[1], sv[2], sv[3]);
  s4[1] = make_float4(sv[4], sv[5], sv[6], sv[7]);
}

// ---- D: output = concat(pop2, relu(SIR2 @ K + bias)) ----
__global__ void __launch_bounds__(256) final_kernel(const float* __restrict__ st1,
                                                    const float* __restrict__ acc1,
                                                    const float* __restrict__ kern,
                                                    const float* __restrict__ bias,
                                                    float* __restrict__ out) {
  __shared__ float klds[12 * 64];
  const int tid = threadIdx.x;
  if (tid < 192) ((float4*)klds)[tid] = ((const float4*)kern)[tid];
  __syncthreads();
  const int p = blockIdx.x * 4 + (tid >> 6);  // b*N+n
  const int c = tid & 63;
  const float4* s4 = (const float4*)(st1 + (size_t)p * 8);
  const float4 l0 = s4[0], l1 = s4[1];
  const float* a = acc1 + (size_t)p * 7;
  const float S[12] = {l0.y, l0.z, l0.w, l1.x, l1.y, l1.z,
                       a[1], a[2], a[3], a[4], a[5], a[6]};
  float sum = bias[c];
#pragma unroll
  for (int f = 0; f < 12; ++f) sum += S[f] * klds[f * 64 + c];
  float* o = out + (size_t)p * 65;
  o[1 + c] = sum > 0.f ? sum : 0.f;
  if (c == 0) o[0] = l0.x + a[0];  // pop2 = pm1 + OD_in1
}

extern "C" void kernel_launch(void* const* d_in, const int* in_sizes, int n_in,
                              void* d_out, int out_size, void* d_ws, size_t ws_size,
                              hipStream_t stream) {
  const float* feat = (const float*)d_in[0];  // (8,2048,4)
  const float* OD   = (const float*)d_in[1];  // (8,2,2048,2048)
  const float* kern = (const float*)d_in[2];  // (12,64)
  const float* bias = (const float*)d_in[3];  // (64,)
  float* out = (float*)d_out;                 // (8,2048,65)
  float* ws = (float*)d_ws;

  float* rs   = ws + RS_OFF;
  float* w0   = ws + W0_OFF;
  float* st0  = ws + ST0_OFF;
  float* w1   = ws + W1_OFF;
  float* st1  = ws + ST1_OFF;
  float* acc0 = ws + ACC0_OFF;
  float* acc1 = ws + ACC1_OFF;

  // zero the atomic accumulators (acc0+acc1 are contiguous)
  hipMemsetAsync(acc0, 0, (size_t)(WS_END - ACC0_OFF) * sizeof(float), stream);

  rowsum_kernel<<<2 * NB / 4, 256, 0, stream>>>(OD, rs);
  prep0_kernel<<<NB / 256, 256, 0, stream>>>(feat, rs, w0, st0);
  dim3 gc(N / 256, N / 256, B);
  colacc_kernel<4, 4><<<gc, 256, 0, stream>>>(OD, 0, w0, acc0);
  prep1_kernel<<<NB / 256, 256, 0, stream>>>(st0, acc0, rs, w1, st1);
  colacc_kernel<7, 8><<<gc, 256, 0, stream>>>(OD, 1, w1, acc1);
  final_kernel<<<NB / 4, 256, 0, stream>>>(st1, acc1, kern, bias, out);
}